// Round 20
// baseline (623.298 us; speedup 1.0000x reference)
//
#include <hip/hip_runtime.h>
#include <hip/hip_bf16.h>

// Problem constants (B=4, H=16, S=2048, D=64, fp32).
#define S_LEN 2048
#define DK    64
#define NT64  32                   // 64-wide k-tiles (attn_pv)
#define NT128 16                   // 128-wide k-tiles (score_sums)
#define O_ELEMS (4 * 16 * 2048 * 64)       // 8388608 = B*H*S*D

typedef float f32x4  __attribute__((ext_vector_type(4)));
typedef short bf16x8 __attribute__((ext_vector_type(8)));
typedef int   i32x4  __attribute__((ext_vector_type(4)));   // nt-load-able
typedef unsigned int u32x4 __attribute__((ext_vector_type(4))); // nt-store-able

static __device__ __forceinline__ unsigned short f2bf(float f) {
  unsigned int u = __builtin_bit_cast(unsigned int, f);
  u += 0x7fffu + ((u >> 16) & 1u);
  return (unsigned short)(u >> 16);
}

// async global->LDS, 16B per lane; LDS dest = wave-uniform base + lane*16
static __device__ __forceinline__ void gload_lds16(const void* g, void* l) {
  __builtin_amdgcn_global_load_lds(
      (const __attribute__((address_space(1))) unsigned int*)g,
      (__attribute__((address_space(3))) unsigned int*)l, 16, 0, 0);
}

// ---------------------------------------------------------------------------
// K fp32 -> bf16 (plain round-to-nearest). grid 8192 x 256.
__global__ __launch_bounds__(256) void cvt_k_kernel(
    const float* __restrict__ k, unsigned short* __restrict__ k_hi) {
  int i = blockIdx.x * 256 + threadIdx.x;
  float4 v = ((const float4*)k)[i];
  ushort4 h;
  h.x = f2bf(v.x); h.y = f2bf(v.y); h.z = f2bf(v.z); h.w = f2bf(v.w);
  ((ushort4*)k_hi)[i] = h;
}

// ---------------------------------------------------------------------------
// V [bh][j][d] fp32 -> V_t [bh][d][j] bf16. grid 2048.
__global__ __launch_bounds__(256) void transpose_v_kernel(
    const float* __restrict__ v, unsigned short* __restrict__ v_t) {
  __shared__ float tile[64][65];
  const int b  = blockIdx.x;
  const int bh = b >> 5;
  const int j0 = (b & 31) << 6;
  const int t  = threadIdx.x;
  #pragma unroll
  for (int i = 0; i < 4; ++i) {
    int flat = i * 256 + t;
    int jl   = flat >> 4;
    int f4   = flat & 15;
    float4 x = *(const float4*)(v + ((size_t)bh * S_LEN + j0 + jl) * DK + f4 * 4);
    tile[jl][f4 * 4 + 0] = x.x;
    tile[jl][f4 * 4 + 1] = x.y;
    tile[jl][f4 * 4 + 2] = x.z;
    tile[jl][f4 * 4 + 3] = x.w;
  }
  __syncthreads();
  #pragma unroll
  for (int i = 0; i < 4; ++i) {
    int flat = i * 256 + t;
    int d    = flat >> 4;
    int jg   = (flat & 15) << 2;
    ushort4 o;
    o.x = f2bf(tile[jg + 0][d]);
    o.y = f2bf(tile[jg + 1][d]);
    o.z = f2bf(tile[jg + 2][d]);
    o.w = f2bf(tile[jg + 3][d]);
    *(ushort4*)(v_t + ((size_t)bh * DK + d) * S_LEN + j0 + jg) = o;
  }
}

// ---------------------------------------------------------------------------
// Pass A kernel (R14 structure, validated): QK^T + mask -> inverted row sums
// + packed mask bits. KVBLK=128, 16 iterations, __syncthreads double-buffer,
// NO manual vmcnt (spill-safe). LDS 36KB -> 4 blocks/CU.
// R20 = R19 retry with ext_vector types for the nt builtins (HIP_vector_type
// int4/uint4 are structs and rejected by __builtin_nontemporal_*).
// Mechanism: the 1.07GB read-once mask stream evicts the L2-resident K_hi
// working set (2MB/XCD); nt bypasses L2 allocation (R18's write-side
// symmetric fix gained +6.5us). Pure cache hint; zero correctness risk.
__global__ __launch_bounds__(256, 4) void score_sums(
    const float* __restrict__ q,
    const int* __restrict__ mask,
    const unsigned short* __restrict__ k_hi,
    unsigned int* __restrict__ bits,
    float* __restrict__ sums_out) {
  const int blk = blockIdx.x;                 // 0..2047
  const int id  = ((blk & 7) << 8) | (blk >> 3);  // XCD-contig bh ranges
  const int bh  = id >> 5;
  const int q0  = (id & 31) << 6;
  const int tid = threadIdx.x;
  const int w   = tid >> 6;
  const int ln  = tid & 63;
  const int l15 = ln & 15;
  const int lq  = ln >> 4;

  __shared__ __align__(16) unsigned short kh_s[2][128][64];  // 32 KB
  __shared__ unsigned int pm_lds[2][4][64][2];               //  4 KB

  const int r8  = ln >> 3, c8 = ln & 7;
  const int swz = c8 ^ r8;
  const size_t kst = ((size_t)bh * S_LEN + 32 * w + r8) * DK + ((size_t)swz << 3);
  auto stage_K = [&](int t, int b) {
    #pragma unroll
    for (int u = 0; u < 4; ++u)
      gload_lds16(k_hi + kst + (size_t)t * (128 * DK) + (size_t)u * (8 * DK),
                  &kh_s[b][32 * w + 8 * u][0]);
  };

  const float* qp = q + ((size_t)bh * S_LEN + q0 + (w << 4) + l15) * DK + (lq << 3);
  const float4 qa0 = *(const float4*)(qp);
  const float4 qb0 = *(const float4*)(qp + 4);
  const float4 qa1 = *(const float4*)(qp + 32);
  const float4 qb1 = *(const float4*)(qp + 36);

  const int* mp4 = mask + ((size_t)bh * S_LEN + q0 + 16 * w + (ln >> 2)) * S_LEN
                        + 4 * (ln & 3);

  bf16x8 qh[2];
  {
    const float sc = 0.125f * 1.4426950408889634f;
    float vv0[8] = {qa0.x, qa0.y, qa0.z, qa0.w, qb0.x, qb0.y, qb0.z, qb0.w};
    float vv1[8] = {qa1.x, qa1.y, qa1.z, qa1.w, qb1.x, qb1.y, qb1.z, qb1.w};
    #pragma unroll
    for (int i = 0; i < 8; ++i) {
      qh[0][i] = (short)f2bf(vv0[i] * sc);
      qh[1][i] = (short)f2bf(vv1[i] * sc);
    }
  }

  auto qk_tile = [&](const unsigned short* kbase, f32x4 (&acc)[8]) {
    #pragma unroll
    for (int s = 0; s < 8; ++s) {
      #pragma unroll
      for (int c = 0; c < 2; ++c) {
        const int off = (s * 16 + l15) * 64 + ((((c << 2) | lq) ^ (l15 & 7)) << 3);
        const bf16x8 bhf = *(const bf16x8*)(kbase + off);
        acc[s] = __builtin_amdgcn_mfma_f32_16x16x32_bf16(qh[c], bhf, acc[s], 0, 0, 0);
      }
    }
  };

  i32x4 mS4[8];
  float sums[4] = {0.f, 0.f, 0.f, 0.f};
  unsigned mwv[4][4];
  #pragma unroll
  for (int r = 0; r < 4; ++r)
    #pragma unroll
    for (int wo = 0; wo < 4; ++wo) mwv[r][wo] = 0u;

#define LOAD_M8(T)                                                           \
  _Pragma("unroll") for (int j = 0; j < 8; ++j)                              \
    mS4[j] = __builtin_nontemporal_load(                                     \
        (const i32x4*)(mp4 + (size_t)(T) * 128 + 16 * j));

#define PACK_WRITE(PBUF)                                                     \
  _Pragma("unroll") for (int h = 0; h < 2; ++h) {                            \
    unsigned p = 0;                                                          \
    _Pragma("unroll") for (int j = 0; j < 4; ++j) {                          \
      const i32x4 m = mS4[4 * h + j];                                        \
      p |= (unsigned)(m[0] != 0) << (4 * j + 0);                             \
      p |= (unsigned)(m[1] != 0) << (4 * j + 1);                             \
      p |= (unsigned)(m[2] != 0) << (4 * j + 2);                             \
      p |= (unsigned)(m[3] != 0) << (4 * j + 3);                             \
    }                                                                        \
    pm_lds[PBUF][w][ln][h] = p;                                              \
  }

  stage_K(0, 0);
  LOAD_M8(0)
  PACK_WRITE(0)
  __syncthreads();

#define SA_BODY(T, BUF)                                                      \
  {                                                                          \
    if ((T) + 1 < NT128) { stage_K((T) + 1, (BUF) ^ 1); LOAD_M8((T) + 1) }   \
    f32x4 acc[8];                                                            \
    _Pragma("unroll") for (int s = 0; s < 8; ++s)                            \
      acc[s] = f32x4{0.f, 0.f, 0.f, 0.f};                                    \
    qk_tile(&kh_s[BUF][0][0], acc);                                          \
    unsigned Qr[4][2];                                                       \
    _Pragma("unroll") for (int r = 0; r < 4; ++r)                            \
      _Pragma("unroll") for (int h = 0; h < 2; ++h)                          \
        Qr[r][h] = pm_lds[BUF][w][(lq << 4) + (r << 2) + (l15 >> 2)][h]      \
                   >> (l15 & 3);                                             \
    _Pragma("unroll") for (int r = 0; r < 4; ++r) {                          \
      _Pragma("unroll") for (int s = 0; s < 8; ++s) {                        \
        const unsigned m = (Qr[r][s >> 2] >> (4 * (s & 3))) & 1u;            \
        mwv[r][(2 * (T) + (s >> 2)) >> 3] |=                                 \
            m << (4 * ((2 * (T) + (s >> 2)) & 7) + (s & 3));                 \
        sums[r] += m ? 0.f : __builtin_amdgcn_exp2f(acc[s][r]);              \
      }                                                                      \
    }                                                                        \
    if ((T) + 1 < NT128) { PACK_WRITE((BUF) ^ 1) }                           \
    __syncthreads();                                                         \
  }

  SA_BODY(0, 0)
  for (int tt = 0; tt < 7; ++tt) {
    SA_BODY(2 * tt + 1, 1)
    SA_BODY(2 * tt + 2, 0)
  }
  SA_BODY(15, 1)

  #pragma unroll
  for (int r = 0; r < 4; ++r) {
    float x = sums[r];
    x += __shfl_xor(x, 1, 64);
    x += __shfl_xor(x, 2, 64);
    x += __shfl_xor(x, 4, 64);
    x += __shfl_xor(x, 8, 64);
    if (l15 == 0) sums_out[id * 64 + (w << 4) + (lq << 2) + r] = 1.0f / x;
  }
  unsigned int* bb = bits + ((size_t)id * 256 + tid) * 16;
  #pragma unroll
  for (int r = 0; r < 4; ++r) {
    u32x4 o;
    o[0] = mwv[r][0]; o[1] = mwv[r][1]; o[2] = mwv[r][2]; o[3] = mwv[r][3];
    __builtin_nontemporal_store(o, (u32x4*)(bb + 4 * r));
  }
#undef SA_BODY
#undef LOAD_M8
#undef PACK_WRITE
}

// ---------------------------------------------------------------------------
// Pass B kernel: R18-VERBATIM (R14 schedule + nontemporal weight stores,
// steady vmcnt(16); validated, 571.5us total).
__global__ __launch_bounds__(256, 4) void attn_pv(
    const float* __restrict__ q,
    const unsigned int* __restrict__ bits,
    const float* __restrict__ sums_in,
    const unsigned short* __restrict__ k_hi,
    const unsigned short* __restrict__ v_t,
    float* __restrict__ out_o,
    float* __restrict__ out_w) {
  const int blk = blockIdx.x;
  const int id  = ((blk & 7) << 8) | (blk >> 3);
  const int bh  = id >> 5;
  const int q0  = (id & 31) << 6;
  const int tid = threadIdx.x;
  const int w   = tid >> 6;
  const int ln  = tid & 63;
  const int l15 = ln & 15;
  const int lq  = ln >> 4;

  __shared__ __align__(16) unsigned short kh_s[2][64][64];  // 16 KB
  __shared__ __align__(16) unsigned short vt_s[2][64][64];  // 16 KB
  __shared__ __align__(16) unsigned short p_lds[4][16][64]; //  8 KB

  const int r8  = ln >> 3, c8 = ln & 7;
  const int swz = c8 ^ r8;
  const size_t kst = ((size_t)bh * S_LEN + 16 * w + r8) * DK + ((size_t)swz << 3);
  const size_t vst = ((size_t)bh * DK + 16 * w + r8) * S_LEN + ((size_t)swz << 3);

  auto stage_K = [&](int t, int b) {
    gload_lds16(k_hi + kst + (size_t)t * (64 * DK),          &kh_s[b][16 * w][0]);
    gload_lds16(k_hi + kst + (size_t)t * (64 * DK) + 8 * DK, &kh_s[b][16 * w + 8][0]);
  };
  auto stage_V = [&](int t, int b) {
    gload_lds16(v_t + vst + (size_t)t * 64,             &vt_s[b][16 * w][0]);
    gload_lds16(v_t + vst + (size_t)t * 64 + 8 * S_LEN, &vt_s[b][16 * w + 8][0]);
  };

  // prologue register loads (OLDER than the stage DMA; drained at PB0 vmcnt(0))
  const float* qp = q + ((size_t)bh * S_LEN + q0 + (w << 4) + l15) * DK + (lq << 3);
  const float4 qa0 = *(const float4*)(qp);
  const float4 qb0 = *(const float4*)(qp + 4);
  const float4 qa1 = *(const float4*)(qp + 32);
  const float4 qb1 = *(const float4*)(qp + 36);
  const uint4* bq = (const uint4*)(bits + ((size_t)id * 256 + tid) * 16);
  uint4 mq[4];
  #pragma unroll
  for (int r = 0; r < 4; ++r) mq[r] = bq[r];
  const float* sp = sums_in + id * 64 + (w << 4) + (lq << 2);
  float sums[4] = {sp[0], sp[1], sp[2], sp[3]};   // already inverted

  bf16x8 qh[2];
  {
    const float sc = 0.125f * 1.4426950408889634f;
    float vv0[8] = {qa0.x, qa0.y, qa0.z, qa0.w, qb0.x, qb0.y, qb0.z, qb0.w};
    float vv1[8] = {qa1.x, qa1.y, qa1.z, qa1.w, qb1.x, qb1.y, qb1.z, qb1.w};
    #pragma unroll
    for (int i = 0; i < 8; ++i) {
      qh[0][i] = (short)f2bf(vv0[i] * sc);
      qh[1][i] = (short)f2bf(vv1[i] * sc);
    }
  }

  const size_t rowb = (size_t)bh * S_LEN + q0 + (w << 4) + (lq << 2);
  const size_t mofs = rowb * S_LEN + l15;
  const size_t oofs = rowb * DK + l15;

  auto qk_tile = [&](const unsigned short* kbase, f32x4 (&acc)[4]) {
    #pragma unroll
    for (int s = 0; s < 4; ++s) {
      #pragma unroll
      for (int c = 0; c < 2; ++c) {
        const int off = (s * 16 + l15) * 64 + ((((c << 2) | lq) ^ (l15 & 7)) << 3);
        const bf16x8 bhf = *(const bf16x8*)(kbase + off);
        acc[s] = __builtin_amdgcn_mfma_f32_16x16x32_bf16(qh[c], bhf, acc[s], 0, 0, 0);
      }
    }
  };

  f32x4 oacc[4];
  #pragma unroll
  for (int s = 0; s < 4; ++s) oacc[s] = f32x4{0.f, 0.f, 0.f, 0.f};

  stage_K(0, 0);
  stage_V(0, 0);

#define PB_BODY(T, BUF, WAITN)                                               \
  {                                                                          \
    asm volatile("s_waitcnt vmcnt(" #WAITN ")" ::: "memory");                \
    __builtin_amdgcn_s_barrier();                                            \
    __builtin_amdgcn_sched_barrier(0);                                       \
    if ((T) + 1 < NT64) { stage_K((T) + 1, (BUF) ^ 1);                       \
                          stage_V((T) + 1, (BUF) ^ 1); }                     \
    __builtin_amdgcn_sched_barrier(0);  /* stages pinned before stores */    \
    f32x4 acc[4];                                                            \
    acc[0] = f32x4{0.f, 0.f, 0.f, 0.f}; acc[1] = f32x4{0.f, 0.f, 0.f, 0.f};  \
    acc[2] = f32x4{0.f, 0.f, 0.f, 0.f}; acc[3] = f32x4{0.f, 0.f, 0.f, 0.f};  \
    qk_tile(&kh_s[BUF][0][0], acc);                                          \
    const int wsel = (T) >> 3;                                               \
    const int sh0 = 4 * ((T) & 7);                                           \
    float* wbase = out_w + mofs + (size_t)(T) * 64;                          \
    _Pragma("unroll") for (int r = 0; r < 4; ++r) {                          \
      const unsigned mword = wsel == 0 ? mq[r].x : wsel == 1 ? mq[r].y       \
                           : wsel == 2 ? mq[r].z : mq[r].w;                  \
      const int row = (lq << 2) + r;                                         \
      _Pragma("unroll") for (int s = 0; s < 4; ++s) {                        \
        const int m = (int)((mword >> (sh0 + s)) & 1u);                      \
        const float e = m ? 0.f : __builtin_amdgcn_exp2f(acc[s][r]);         \
        const float wn = e * sums[r];                                        \
        __builtin_nontemporal_store(wn, &wbase[(size_t)r * S_LEN + s * 16]); \
        const int chunk = ((s << 1) | (l15 >> 3)) ^ (row & 7);               \
        p_lds[w][row][(chunk << 3) | (l15 & 7)] = f2bf(wn);                  \
      }                                                                      \
    }                                                                        \
    __builtin_amdgcn_wave_barrier();                                         \
    _Pragma("unroll") for (int c = 0; c < 2; ++c) {                          \
      const bf16x8 pa = *(const bf16x8*)                                     \
          &p_lds[w][l15][((((c << 2) | lq)) ^ (l15 & 7)) << 3];              \
      _Pragma("unroll") for (int s = 0; s < 4; ++s) {                        \
        const int off = (s * 16 + l15) * 64 +                                \
                        ((((c << 2) | lq) ^ (l15 & 7)) << 3);                \
        const bf16x8 vb = *(const bf16x8*)(&vt_s[BUF][0][0] + off);          \
        oacc[s] = __builtin_amdgcn_mfma_f32_16x16x32_bf16(pa, vb, oacc[s],   \
                                                          0, 0, 0);          \
      }                                                                      \
    }                                                                        \
    __builtin_amdgcn_wave_barrier();                                         \
  }

  PB_BODY(0, 0, 0)
  for (int tt = 0; tt < 15; ++tt) {
    PB_BODY(2 * tt + 1, 1, 16)
    PB_BODY(2 * tt + 2, 0, 16)
  }
  PB_BODY(31, 1, 16)

  #pragma unroll
  for (int s = 0; s < 4; ++s) {
    #pragma unroll
    for (int r = 0; r < 4; ++r) {
      out_o[oofs + (size_t)r * DK + s * 16] = oacc[s][r];
    }
  }
#undef PB_BODY
}

// ---------------------------------------------------------------------------
extern "C" void kernel_launch(void* const* d_in, const int* in_sizes, int n_in,
                              void* d_out, int out_size, void* d_ws, size_t ws_size,
                              hipStream_t stream) {
  (void)in_sizes; (void)n_in; (void)out_size; (void)ws_size;
  const float* q = (const float*)d_in[0];
  const float* k = (const float*)d_in[1];
  const float* v = (const float*)d_in[2];
  const int* mask = (const int*)d_in[3];      // bool_ -> int32

  float* out_o = (float*)d_out;               // [B,H,S,D] fp32
  float* out_w = out_o + (size_t)O_ELEMS;     // [B,H,S,S] fp32

  // workspace: K bf16 16.8MB + V_t bf16 16.8MB + bits 33.6MB + sums 0.5MB
  unsigned short* k_hi = (unsigned short*)d_ws;
  unsigned short* v_t  = k_hi + (size_t)O_ELEMS;
  unsigned int*   bits = (unsigned int*)(v_t + (size_t)O_ELEMS);
  float*          sums = (float*)(bits + (size_t)2048 * 256 * 16);

  cvt_k_kernel<<<8192, 256, 0, stream>>>(k, k_hi);
  transpose_v_kernel<<<2048, 256, 0, stream>>>(v, v_t);
  score_sums<<<2048, 256, 0, stream>>>(q, mask, k_hi, bits, sums);
  attn_pv<<<2048, 256, 0, stream>>>(q, bits, sums, k_hi, v_t, out_o, out_w);
}

// Round 21
// 571.519 us; speedup vs baseline: 1.0906x; 1.0906x over previous
//
#include <hip/hip_runtime.h>
#include <hip/hip_bf16.h>

// Problem constants (B=4, H=16, S=2048, D=64, fp32).
#define S_LEN 2048
#define DK    64
#define NT64  32                   // 64-wide k-tiles (attn_pv)
#define NT128 16                   // 128-wide k-tiles (score_sums)
#define O_ELEMS (4 * 16 * 2048 * 64)       // 8388608 = B*H*S*D

typedef float f32x4  __attribute__((ext_vector_type(4)));
typedef short bf16x8 __attribute__((ext_vector_type(8)));

static __device__ __forceinline__ unsigned short f2bf(float f) {
  unsigned int u = __builtin_bit_cast(unsigned int, f);
  u += 0x7fffu + ((u >> 16) & 1u);
  return (unsigned short)(u >> 16);
}

// async global->LDS, 16B per lane; LDS dest = wave-uniform base + lane*16
static __device__ __forceinline__ void gload_lds16(const void* g, void* l) {
  __builtin_amdgcn_global_load_lds(
      (const __attribute__((address_space(1))) unsigned int*)g,
      (__attribute__((address_space(3))) unsigned int*)l, 16, 0, 0);
}

// ---------------------------------------------------------------------------
// K fp32 -> bf16 (plain round-to-nearest). grid 8192 x 256.
__global__ __launch_bounds__(256) void cvt_k_kernel(
    const float* __restrict__ k, unsigned short* __restrict__ k_hi) {
  int i = blockIdx.x * 256 + threadIdx.x;
  float4 v = ((const float4*)k)[i];
  ushort4 h;
  h.x = f2bf(v.x); h.y = f2bf(v.y); h.z = f2bf(v.z); h.w = f2bf(v.w);
  ((ushort4*)k_hi)[i] = h;
}

// ---------------------------------------------------------------------------
// V [bh][j][d] fp32 -> V_t [bh][d][j] bf16. grid 2048.
__global__ __launch_bounds__(256) void transpose_v_kernel(
    const float* __restrict__ v, unsigned short* __restrict__ v_t) {
  __shared__ float tile[64][65];
  const int b  = blockIdx.x;
  const int bh = b >> 5;
  const int j0 = (b & 31) << 6;
  const int t  = threadIdx.x;
  #pragma unroll
  for (int i = 0; i < 4; ++i) {
    int flat = i * 256 + t;
    int jl   = flat >> 4;
    int f4   = flat & 15;
    float4 x = *(const float4*)(v + ((size_t)bh * S_LEN + j0 + jl) * DK + f4 * 4);
    tile[jl][f4 * 4 + 0] = x.x;
    tile[jl][f4 * 4 + 1] = x.y;
    tile[jl][f4 * 4 + 2] = x.z;
    tile[jl][f4 * 4 + 3] = x.w;
  }
  __syncthreads();
  #pragma unroll
  for (int i = 0; i < 4; ++i) {
    int flat = i * 256 + t;
    int d    = flat >> 4;
    int jg   = (flat & 15) << 2;
    ushort4 o;
    o.x = f2bf(tile[jg + 0][d]);
    o.y = f2bf(tile[jg + 1][d]);
    o.z = f2bf(tile[jg + 2][d]);
    o.w = f2bf(tile[jg + 3][d]);
    *(ushort4*)(v_t + ((size_t)bh * DK + d) * S_LEN + j0 + jg) = o;
  }
}

// ---------------------------------------------------------------------------
// Pass A kernel (R14-VERBATIM, validated): QK^T + mask -> inverted row sums
// + packed mask bits. KVBLK=128, 16 iterations, __syncthreads double-buffer,
// NO manual vmcnt (spill-safe). LDS 36KB -> 4 blocks/CU. Plain (cached)
// mask loads -- R20 proved nt loads regress (-52us: lose L2 read-merging).
__global__ __launch_bounds__(256, 4) void score_sums(
    const float* __restrict__ q,
    const int* __restrict__ mask,
    const unsigned short* __restrict__ k_hi,
    unsigned int* __restrict__ bits,
    float* __restrict__ sums_out) {
  const int blk = blockIdx.x;                 // 0..2047
  const int id  = ((blk & 7) << 8) | (blk >> 3);  // XCD-contig bh ranges
  const int bh  = id >> 5;
  const int q0  = (id & 31) << 6;
  const int tid = threadIdx.x;
  const int w   = tid >> 6;
  const int ln  = tid & 63;
  const int l15 = ln & 15;
  const int lq  = ln >> 4;

  __shared__ __align__(16) unsigned short kh_s[2][128][64];  // 32 KB
  __shared__ unsigned int pm_lds[2][4][64][2];               //  4 KB

  const int r8  = ln >> 3, c8 = ln & 7;
  const int swz = c8 ^ r8;
  const size_t kst = ((size_t)bh * S_LEN + 32 * w + r8) * DK + ((size_t)swz << 3);
  auto stage_K = [&](int t, int b) {
    #pragma unroll
    for (int u = 0; u < 4; ++u)
      gload_lds16(k_hi + kst + (size_t)t * (128 * DK) + (size_t)u * (8 * DK),
                  &kh_s[b][32 * w + 8 * u][0]);
  };

  const float* qp = q + ((size_t)bh * S_LEN + q0 + (w << 4) + l15) * DK + (lq << 3);
  const float4 qa0 = *(const float4*)(qp);
  const float4 qb0 = *(const float4*)(qp + 4);
  const float4 qa1 = *(const float4*)(qp + 32);
  const float4 qb1 = *(const float4*)(qp + 36);

  const int* mp4 = mask + ((size_t)bh * S_LEN + q0 + 16 * w + (ln >> 2)) * S_LEN
                        + 4 * (ln & 3);

  bf16x8 qh[2];
  {
    const float sc = 0.125f * 1.4426950408889634f;
    float vv0[8] = {qa0.x, qa0.y, qa0.z, qa0.w, qb0.x, qb0.y, qb0.z, qb0.w};
    float vv1[8] = {qa1.x, qa1.y, qa1.z, qa1.w, qb1.x, qb1.y, qb1.z, qb1.w};
    #pragma unroll
    for (int i = 0; i < 8; ++i) {
      qh[0][i] = (short)f2bf(vv0[i] * sc);
      qh[1][i] = (short)f2bf(vv1[i] * sc);
    }
  }

  auto qk_tile = [&](const unsigned short* kbase, f32x4 (&acc)[8]) {
    #pragma unroll
    for (int s = 0; s < 8; ++s) {
      #pragma unroll
      for (int c = 0; c < 2; ++c) {
        const int off = (s * 16 + l15) * 64 + ((((c << 2) | lq) ^ (l15 & 7)) << 3);
        const bf16x8 bhf = *(const bf16x8*)(kbase + off);
        acc[s] = __builtin_amdgcn_mfma_f32_16x16x32_bf16(qh[c], bhf, acc[s], 0, 0, 0);
      }
    }
  };

  int4 mS4[8];
  float sums[4] = {0.f, 0.f, 0.f, 0.f};
  unsigned mwv[4][4];
  #pragma unroll
  for (int r = 0; r < 4; ++r)
    #pragma unroll
    for (int wo = 0; wo < 4; ++wo) mwv[r][wo] = 0u;

#define LOAD_M8(T)                                                           \
  _Pragma("unroll") for (int j = 0; j < 8; ++j)                              \
    mS4[j] = *(const int4*)(mp4 + (size_t)(T) * 128 + 16 * j);

#define PACK_WRITE(PBUF)                                                     \
  _Pragma("unroll") for (int h = 0; h < 2; ++h) {                            \
    unsigned p = 0;                                                          \
    _Pragma("unroll") for (int j = 0; j < 4; ++j) {                          \
      const int4 m = mS4[4 * h + j];                                         \
      p |= (unsigned)(m.x != 0) << (4 * j + 0);                              \
      p |= (unsigned)(m.y != 0) << (4 * j + 1);                              \
      p |= (unsigned)(m.z != 0) << (4 * j + 2);                              \
      p |= (unsigned)(m.w != 0) << (4 * j + 3);                              \
    }                                                                        \
    pm_lds[PBUF][w][ln][h] = p;                                              \
  }

  stage_K(0, 0);
  LOAD_M8(0)
  PACK_WRITE(0)
  __syncthreads();

#define SA_BODY(T, BUF)                                                      \
  {                                                                          \
    if ((T) + 1 < NT128) { stage_K((T) + 1, (BUF) ^ 1); LOAD_M8((T) + 1) }   \
    f32x4 acc[8];                                                            \
    _Pragma("unroll") for (int s = 0; s < 8; ++s)                            \
      acc[s] = f32x4{0.f, 0.f, 0.f, 0.f};                                    \
    qk_tile(&kh_s[BUF][0][0], acc);                                          \
    unsigned Qr[4][2];                                                       \
    _Pragma("unroll") for (int r = 0; r < 4; ++r)                            \
      _Pragma("unroll") for (int h = 0; h < 2; ++h)                          \
        Qr[r][h] = pm_lds[BUF][w][(lq << 4) + (r << 2) + (l15 >> 2)][h]      \
                   >> (l15 & 3);                                             \
    _Pragma("unroll") for (int r = 0; r < 4; ++r) {                          \
      _Pragma("unroll") for (int s = 0; s < 8; ++s) {                        \
        const unsigned m = (Qr[r][s >> 2] >> (4 * (s & 3))) & 1u;            \
        mwv[r][(2 * (T) + (s >> 2)) >> 3] |=                                 \
            m << (4 * ((2 * (T) + (s >> 2)) & 7) + (s & 3));                 \
        sums[r] += m ? 0.f : __builtin_amdgcn_exp2f(acc[s][r]);              \
      }                                                                      \
    }                                                                        \
    if ((T) + 1 < NT128) { PACK_WRITE((BUF) ^ 1) }                           \
    __syncthreads();                                                         \
  }

  SA_BODY(0, 0)
  for (int tt = 0; tt < 7; ++tt) {
    SA_BODY(2 * tt + 1, 1)
    SA_BODY(2 * tt + 2, 0)
  }
  SA_BODY(15, 1)

  #pragma unroll
  for (int r = 0; r < 4; ++r) {
    float x = sums[r];
    x += __shfl_xor(x, 1, 64);
    x += __shfl_xor(x, 2, 64);
    x += __shfl_xor(x, 4, 64);
    x += __shfl_xor(x, 8, 64);
    if (l15 == 0) sums_out[id * 64 + (w << 4) + (lq << 2) + r] = 1.0f / x;
  }
  unsigned int* bb = bits + ((size_t)id * 256 + tid) * 16;
  #pragma unroll
  for (int r = 0; r < 4; ++r)
    *(uint4*)(bb + 4 * r) = make_uint4(mwv[r][0], mwv[r][1], mwv[r][2], mwv[r][3]);
#undef SA_BODY
#undef LOAD_M8
#undef PACK_WRITE
}

// ---------------------------------------------------------------------------
// Pass B kernel: R14 schedule + nontemporal weight stores (R18, validated
// best: 571.5us total). Steady top vmcnt(16) = stage K/V(T) 4 oldest
// retired, stores(T-1) 16 may fly; masks/sums from prologue registers.
__global__ __launch_bounds__(256, 4) void attn_pv(
    const float* __restrict__ q,
    const unsigned int* __restrict__ bits,
    const float* __restrict__ sums_in,
    const unsigned short* __restrict__ k_hi,
    const unsigned short* __restrict__ v_t,
    float* __restrict__ out_o,
    float* __restrict__ out_w) {
  const int blk = blockIdx.x;
  const int id  = ((blk & 7) << 8) | (blk >> 3);
  const int bh  = id >> 5;
  const int q0  = (id & 31) << 6;
  const int tid = threadIdx.x;
  const int w   = tid >> 6;
  const int ln  = tid & 63;
  const int l15 = ln & 15;
  const int lq  = ln >> 4;

  __shared__ __align__(16) unsigned short kh_s[2][64][64];  // 16 KB
  __shared__ __align__(16) unsigned short vt_s[2][64][64];  // 16 KB
  __shared__ __align__(16) unsigned short p_lds[4][16][64]; //  8 KB

  const int r8  = ln >> 3, c8 = ln & 7;
  const int swz = c8 ^ r8;
  const size_t kst = ((size_t)bh * S_LEN + 16 * w + r8) * DK + ((size_t)swz << 3);
  const size_t vst = ((size_t)bh * DK + 16 * w + r8) * S_LEN + ((size_t)swz << 3);

  auto stage_K = [&](int t, int b) {
    gload_lds16(k_hi + kst + (size_t)t * (64 * DK),          &kh_s[b][16 * w][0]);
    gload_lds16(k_hi + kst + (size_t)t * (64 * DK) + 8 * DK, &kh_s[b][16 * w + 8][0]);
  };
  auto stage_V = [&](int t, int b) {
    gload_lds16(v_t + vst + (size_t)t * 64,             &vt_s[b][16 * w][0]);
    gload_lds16(v_t + vst + (size_t)t * 64 + 8 * S_LEN, &vt_s[b][16 * w + 8][0]);
  };

  // prologue register loads (OLDER than the stage DMA; drained at PB0 vmcnt(0))
  const float* qp = q + ((size_t)bh * S_LEN + q0 + (w << 4) + l15) * DK + (lq << 3);
  const float4 qa0 = *(const float4*)(qp);
  const float4 qb0 = *(const float4*)(qp + 4);
  const float4 qa1 = *(const float4*)(qp + 32);
  const float4 qb1 = *(const float4*)(qp + 36);
  const uint4* bq = (const uint4*)(bits + ((size_t)id * 256 + tid) * 16);
  uint4 mq[4];
  #pragma unroll
  for (int r = 0; r < 4; ++r) mq[r] = bq[r];
  const float* sp = sums_in + id * 64 + (w << 4) + (lq << 2);
  float sums[4] = {sp[0], sp[1], sp[2], sp[3]};   // already inverted

  bf16x8 qh[2];
  {
    const float sc = 0.125f * 1.4426950408889634f;
    float vv0[8] = {qa0.x, qa0.y, qa0.z, qa0.w, qb0.x, qb0.y, qb0.z, qb0.w};
    float vv1[8] = {qa1.x, qa1.y, qa1.z, qa1.w, qb1.x, qb1.y, qb1.z, qb1.w};
    #pragma unroll
    for (int i = 0; i < 8; ++i) {
      qh[0][i] = (short)f2bf(vv0[i] * sc);
      qh[1][i] = (short)f2bf(vv1[i] * sc);
    }
  }

  const size_t rowb = (size_t)bh * S_LEN + q0 + (w << 4) + (lq << 2);
  const size_t mofs = rowb * S_LEN + l15;
  const size_t oofs = rowb * DK + l15;

  auto qk_tile = [&](const unsigned short* kbase, f32x4 (&acc)[4]) {
    #pragma unroll
    for (int s = 0; s < 4; ++s) {
      #pragma unroll
      for (int c = 0; c < 2; ++c) {
        const int off = (s * 16 + l15) * 64 + ((((c << 2) | lq) ^ (l15 & 7)) << 3);
        const bf16x8 bhf = *(const bf16x8*)(kbase + off);
        acc[s] = __builtin_amdgcn_mfma_f32_16x16x32_bf16(qh[c], bhf, acc[s], 0, 0, 0);
      }
    }
  };

  f32x4 oacc[4];
  #pragma unroll
  for (int s = 0; s < 4; ++s) oacc[s] = f32x4{0.f, 0.f, 0.f, 0.f};

  stage_K(0, 0);
  stage_V(0, 0);

#define PB_BODY(T, BUF, WAITN)                                               \
  {                                                                          \
    asm volatile("s_waitcnt vmcnt(" #WAITN ")" ::: "memory");                \
    __builtin_amdgcn_s_barrier();                                            \
    __builtin_amdgcn_sched_barrier(0);                                       \
    if ((T) + 1 < NT64) { stage_K((T) + 1, (BUF) ^ 1);                       \
                          stage_V((T) + 1, (BUF) ^ 1); }                     \
    __builtin_amdgcn_sched_barrier(0);  /* stages pinned before stores */    \
    f32x4 acc[4];                                                            \
    acc[0] = f32x4{0.f, 0.f, 0.f, 0.f}; acc[1] = f32x4{0.f, 0.f, 0.f, 0.f};  \
    acc[2] = f32x4{0.f, 0.f, 0.f, 0.f}; acc[3] = f32x4{0.f, 0.f, 0.f, 0.f};  \
    qk_tile(&kh_s[BUF][0][0], acc);                                          \
    const int wsel = (T) >> 3;                                               \
    const int sh0 = 4 * ((T) & 7);                                           \
    float* wbase = out_w + mofs + (size_t)(T) * 64;                          \
    _Pragma("unroll") for (int r = 0; r < 4; ++r) {                          \
      const unsigned mword = wsel == 0 ? mq[r].x : wsel == 1 ? mq[r].y       \
                           : wsel == 2 ? mq[r].z : mq[r].w;                  \
      const int row = (lq << 2) + r;                                         \
      _Pragma("unroll") for (int s = 0; s < 4; ++s) {                        \
        const int m = (int)((mword >> (sh0 + s)) & 1u);                      \
        const float e = m ? 0.f : __builtin_amdgcn_exp2f(acc[s][r]);         \
        const float wn = e * sums[r];                                        \
        __builtin_nontemporal_store(wn, &wbase[(size_t)r * S_LEN + s * 16]); \
        const int chunk = ((s << 1) | (l15 >> 3)) ^ (row & 7);               \
        p_lds[w][row][(chunk << 3) | (l15 & 7)] = f2bf(wn);                  \
      }                                                                      \
    }                                                                        \
    __builtin_amdgcn_wave_barrier();                                         \
    _Pragma("unroll") for (int c = 0; c < 2; ++c) {                          \
      const bf16x8 pa = *(const bf16x8*)                                     \
          &p_lds[w][l15][((((c << 2) | lq)) ^ (l15 & 7)) << 3];              \
      _Pragma("unroll") for (int s = 0; s < 4; ++s) {                        \
        const int off = (s * 16 + l15) * 64 +                                \
                        ((((c << 2) | lq) ^ (l15 & 7)) << 3);                \
        const bf16x8 vb = *(const bf16x8*)(&vt_s[BUF][0][0] + off);          \
        oacc[s] = __builtin_amdgcn_mfma_f32_16x16x32_bf16(pa, vb, oacc[s],   \
                                                          0, 0, 0);          \
      }                                                                      \
    }                                                                        \
    __builtin_amdgcn_wave_barrier();                                         \
  }

  PB_BODY(0, 0, 0)
  for (int tt = 0; tt < 15; ++tt) {
    PB_BODY(2 * tt + 1, 1, 16)
    PB_BODY(2 * tt + 2, 0, 16)
  }
  PB_BODY(31, 1, 16)

  #pragma unroll
  for (int s = 0; s < 4; ++s) {
    #pragma unroll
    for (int r = 0; r < 4; ++r) {
      out_o[oofs + (size_t)r * DK + s * 16] = oacc[s][r];
    }
  }
#undef PB_BODY
}

// ---------------------------------------------------------------------------
extern "C" void kernel_launch(void* const* d_in, const int* in_sizes, int n_in,
                              void* d_out, int out_size, void* d_ws, size_t ws_size,
                              hipStream_t stream) {
  (void)in_sizes; (void)n_in; (void)out_size; (void)ws_size;
  const float* q = (const float*)d_in[0];
  const float* k = (const float*)d_in[1];
  const float* v = (const float*)d_in[2];
  const int* mask = (const int*)d_in[3];      // bool_ -> int32

  float* out_o = (float*)d_out;               // [B,H,S,D] fp32
  float* out_w = out_o + (size_t)O_ELEMS;     // [B,H,S,S] fp32

  // workspace: K bf16 16.8MB + V_t bf16 16.8MB + bits 33.6MB + sums 0.5MB
  unsigned short* k_hi = (unsigned short*)d_ws;
  unsigned short* v_t  = k_hi + (size_t)O_ELEMS;
  unsigned int*   bits = (unsigned int*)(v_t + (size_t)O_ELEMS);
  float*          sums = (float*)(bits + (size_t)2048 * 256 * 16);

  cvt_k_kernel<<<8192, 256, 0, stream>>>(k, k_hi);
  transpose_v_kernel<<<2048, 256, 0, stream>>>(v, v_t);
  score_sums<<<2048, 256, 0, stream>>>(q, mask, k_hi, bits, sums);
  attn_pv<<<2048, 256, 0, stream>>>(q, bits, sums, k_hi, v_t, out_o, out_w);
}